// Round 9
// baseline (663.140 us; speedup 1.0000x reference)
//
#include <hip/hip_runtime.h>
#include <math.h>

#define T_LEN 3000
#define HID 64

typedef _Float16 f16;
typedef f16 f16x8 __attribute__((ext_vector_type(8)));
typedef float f32x4 __attribute__((ext_vector_type(4)));

#define NLOG2E  (-1.4426950408889634f)   // -log2(e)
#define N2LOG2E (-2.8853900817779268f)   // -2*log2(e)

__device__ __forceinline__ float bcast_lane(float v, int j) {
    return __builtin_bit_cast(float,
        __builtin_amdgcn_readlane(__builtin_bit_cast(int, v), j));
}

// R15 = R14 + instruction-placement fixes in the exposed ds_read window.
// R14 post-mortem: tail surgery across R13/R14 bought ~7cy total -> the tail
// is NOT the critical path. Step (490cy) = write + lgkm drain + s_barrier
// (~40-80) + ds_read exposed latency (~120-140) + 6-MFMA segment (~96 issue
// + dep) + r->n trans chain (~90). Structural floor ~400-420cy. Rejected by
// arithmetic: single-wave no-barrier (384cy MFMA block + redistribution =
// worse), K/gate-split over 8+ waves (adds an LDS-RT reduction to save 48cy
// issue), skewed 2-element pipelining (hides latency but wall = stepcy x T
// with B=#CUs -- R12's theorem).
// Changes:
//  1. sched_barrier(0) right after the two ds_read_b128: compiler cannot
//     hoist readlane/pre-term VALU above the load issue -- every op placed
//     before the loads adds 1:1 to exposed latency; after, it hides free.
//  2. xt/pre-terms kept inside the read-latency window (post-barrier).
//  3. tail -> ds_write -> refill-branch -> barrier packing (source order).
// Fragment math identical to R11/R14 (harness-verified, absmax 4.9e-4).
__global__ __launch_bounds__(256, 1)
void gru_sched(
    const float* __restrict__ x,     // (B, T, 1)
    const float* __restrict__ W_ih,  // (192, 1)
    const float* __restrict__ W_hh,  // (192, 64)
    const float* __restrict__ b_ih,  // (192,)
    const float* __restrict__ b_hh,  // (192,)
    const float* __restrict__ W_fc,  // (1, 64)
    const float* __restrict__ b_fc,  // (1,)
    float* __restrict__ out)         // (B,)
{
    const int tid = threadIdx.x;
    const int w   = tid >> 6;      // wave 0..3 -> owns units 16w..16w+15
    const int l   = tid & 63;
    const int col = l & 15;
    const int grp = l >> 4;        // k-group (redundant dim for gate math)
    const int u   = 16 * w + col;  // this lane's hidden unit
    const int b   = blockIdx.x;
    const long xbase = (long)b * T_LEN;

    __shared__ __align__(16) f16 hbuf[2][HID];  // double-buffered h (f16)
    __shared__ float hf32[HID];                 // epilogue (f32 exact)

    // ---- one-time: this wave's W_hh tiles -> B fragments (f16) ----
    // B slot (lane, elem j) = W_hh[64*g + 16*w + col][8*grp + 32*hf + j]
    f16x8 Bf[3][2];
#pragma unroll
    for (int g = 0; g < 3; ++g) {
#pragma unroll
        for (int hf = 0; hf < 2; ++hf) {
            const float* p = W_hh + (size_t)(64 * g + 16 * w + col) * HID
                           + 8 * grp + 32 * hf;
            const float4 a = *reinterpret_cast<const float4*>(p);
            const float4 c = *reinterpret_cast<const float4*>(p + 4);
            f16x8 v;
            v[0] = (f16)a.x; v[1] = (f16)a.y; v[2] = (f16)a.z; v[3] = (f16)a.w;
            v[4] = (f16)c.x; v[5] = (f16)c.y; v[6] = (f16)c.z; v[7] = (f16)c.w;
            Bf[g][hf] = v;
        }
    }

    // per-unit scalars, pre-scaled by the exp2 constants (off-path fusion)
    const float wihr2 = W_ih[u]        * NLOG2E;
    const float wihz2 = W_ih[64 + u]   * NLOG2E;
    const float wihn2 = W_ih[128 + u]  * N2LOG2E;
    const float br2   = (b_ih[u]        + b_hh[u])        * NLOG2E;
    const float bz2   = (b_ih[64 + u]   + b_hh[64 + u])   * NLOG2E;
    const float bin2  = b_ih[128 + u]  * N2LOG2E;
    const float bhn2  = b_hh[128 + u]  * N2LOG2E;

    // x window in registers: lane j holds x[t0 + j]; broadcast via readlane
    float xwin = x[xbase + l];
    float xnxt = (64 + l < T_LEN) ? x[xbase + 64 + l] : 0.0f;

    if (tid < HID) hbuf[0][tid] = (f16)0.0f;
    __syncthreads();

    float h = 0.0f;  // this lane's unit value (fp32)
    const f32x4 zf = {0.f, 0.f, 0.f, 0.f};

    // loop-invariant LDS addresses
    const f16x8* s0A = reinterpret_cast<const f16x8*>(hbuf[0]) + grp;
    const f16x8* s0B = s0A + 4;
    const f16x8* s1A = reinterpret_cast<const f16x8*>(hbuf[1]) + grp;
    const f16x8* s1B = s1A + 4;
    f16* d0 = &hbuf[0][u];
    f16* d1 = &hbuf[1][u];

    auto step = [&](const f16x8* aP, const f16x8* bP, f16* dstu, int t) {
        const int j = t & 63;

        // 1) loads FIRST -- pinned by the sched_barrier below
        const f16x8 A0 = *aP;             // h[8g..8g+7]       (ds_read_b128)
        const f16x8 A1 = *bP;             // h[32+8g..32+8g+7]
        __builtin_amdgcn_sched_barrier(0);  // nothing hoists above the reads

        // 2) fill the read-latency window with the only available work
        const float xt    = bcast_lane(xwin, j);
        const float pre_r = fmaf(xt, wihr2, br2);
        const float pre_z = fmaf(xt, wihz2, bz2);
        const float pre_n = fmaf(xt, wihn2, bin2);

        // 3) 6 MFMAs (16cy wave-block each); C-chained pairs (AGPR forward)
        f32x4 pr = __builtin_amdgcn_mfma_f32_16x16x32_f16(A0, Bf[0][0], zf, 0, 0, 0);
        f32x4 pz = __builtin_amdgcn_mfma_f32_16x16x32_f16(A0, Bf[1][0], zf, 0, 0, 0);
        f32x4 pn = __builtin_amdgcn_mfma_f32_16x16x32_f16(A0, Bf[2][0], zf, 0, 0, 0);
        f32x4 qr = __builtin_amdgcn_mfma_f32_16x16x32_f16(A1, Bf[0][1], pr, 0, 0, 0);
        f32x4 qz = __builtin_amdgcn_mfma_f32_16x16x32_f16(A1, Bf[1][1], pz, 0, 0, 0);
        f32x4 qn = __builtin_amdgcn_mfma_f32_16x16x32_f16(A1, Bf[2][1], pn, 0, 0, 0);

        // 4) minimal dependent tails
        const float r = __builtin_amdgcn_rcpf(
            1.0f + __builtin_amdgcn_exp2f(fmaf(qr[0], NLOG2E, pre_r)));
        const float hn2 = fmaf(qn[0], N2LOG2E, bhn2);
        const float z = __builtin_amdgcn_rcpf(
            1.0f + __builtin_amdgcn_exp2f(fmaf(qz[0], NLOG2E, pre_z)));
        const float zh  = z * h;
        const float omz = 1.0f - z;
        const float n = fmaf(2.0f, __builtin_amdgcn_rcpf(
            1.0f + __builtin_amdgcn_exp2f(fmaf(r, hn2, pre_n))), -1.0f);
        h = fmaf(omz, n, zh);   // (1-z)*n + z*h

        // 5) write -> refill (rare, uniform branch) -> barrier
        *dstu = (f16)h;         // unconditional: 4 lanes, same addr+value
        if (j == 63) {
            xwin = xnxt;                   // issued 64 steps ago -> landed
            const int idx = t + 65 + l;
            xnxt = (idx < T_LEN) ? x[xbase + idx] : 0.0f;
        }
        // LDS-only drain + barrier (no vmcnt drain -> x slack survives)
        asm volatile("s_waitcnt lgkmcnt(0)\n\ts_barrier" ::: "memory");
    };

    for (int t = 0; t < T_LEN; t += 2) {   // T_LEN even: clean pingpong
        step(s0A, s0B, d1, t);
        step(s1A, s1B, d0, t + 1);
    }

    // ---- epilogue: out[b] = h . W_fc + b_fc (fp32, exact register h) ----
    hf32[u] = h;   // unconditional, same value per u
    __syncthreads();
    if (tid < HID) {
        float v = hf32[tid] * W_fc[tid];
#pragma unroll
        for (int off = 32; off > 0; off >>= 1) v += __shfl_down(v, off);
        if (tid == 0) out[b] = v + b_fc[0];
    }
}

extern "C" void kernel_launch(void* const* d_in, const int* in_sizes, int n_in,
                              void* d_out, int out_size, void* d_ws, size_t ws_size,
                              hipStream_t stream) {
    const float* x    = (const float*)d_in[0];
    const float* W_ih = (const float*)d_in[1];
    const float* W_hh = (const float*)d_in[2];
    const float* b_ih = (const float*)d_in[3];
    const float* b_hh = (const float*)d_in[4];
    const float* W_fc = (const float*)d_in[5];
    const float* b_fc = (const float*)d_in[6];
    float* out = (float*)d_out;

    const int B = 256;  // in_sizes[0] = B*T = 768000 -> B=256, T=3000
    gru_sched<<<B, 256, 0, stream>>>(x, W_ih, W_hh, b_ih, b_hh, W_fc, b_fc, out);
}